// Round 8
// baseline (1070.681 us; speedup 1.0000x reference)
//
#include <hip/hip_runtime.h>
#include <math.h>

#define TLEN 256
#define BATCH 4
#define DMODEL 768
#define DINNER 1536
#define NSTATE 16
#define DTRANK 48
#define NLAYER 4
#define NTOK 1024

#define S_IP 2359296
#define S_OP 1179648
#define S_XP2 196608            /* 128 x 1536 zero-padded */
#define S_DT 98304              /* 1536 x 64 zero-padded  */
#define WL (S_IP + S_OP + S_XP2 + S_DT)
#define NB_W (WL / 1024)        /* 3744 blocks per layer */
#define NB_WALL (NB_W * NLAYER)
#define NB_E (NTOK * DMODEL / 256)

typedef __bf16 bf16x8 __attribute__((ext_vector_type(8)));
typedef float f32x4 __attribute__((ext_vector_type(4)));

__device__ inline unsigned short f2b(float f) {
    union { float f; unsigned u; } v;
    v.f = f;
    unsigned r = (v.u + 0x7fffu + ((v.u >> 16) & 1u)) >> 16;  // RNE
    return (unsigned short)r;
}
__device__ inline float b2f(unsigned short u) {
    union { unsigned u; float f; } v;
    v.u = ((unsigned)u) << 16;
    return v.f;
}

__device__ inline void gload16(const void* g, void* l) {
    __builtin_amdgcn_global_load_lds(
        (const __attribute__((address_space(1))) void*)g,
        (__attribute__((address_space(3))) void*)l, 16, 0, 0);
}

// 16-lane sum via DPP (quad xor1, xor2, then row_ror 4, 8) — no DS ops.
__device__ inline float red16(float p) {
    p += __int_as_float(__builtin_amdgcn_update_dpp(0, __float_as_int(p), 0xB1, 0xf, 0xf, true));
    p += __int_as_float(__builtin_amdgcn_update_dpp(0, __float_as_int(p), 0x4E, 0xf, 0xf, true));
    p += __int_as_float(__builtin_amdgcn_update_dpp(0, __float_as_int(p), 0x124, 0xf, 0xf, true));
    p += __int_as_float(__builtin_amdgcn_update_dpp(0, __float_as_int(p), 0x128, 0xf, 0xf, true));
    return p;
}

// ---------------- prep: all-layer weight convert + embed, one dispatch ----------------
__global__ __launch_bounds__(256) void prep_k(const float* __restrict__ ipw,
                                              const float* __restrict__ opw,
                                              const float* __restrict__ xpw,
                                              const float* __restrict__ dpw,
                                              const int* __restrict__ ids,
                                              const float* __restrict__ emb,
                                              const float* __restrict__ pos,
                                              unsigned short* __restrict__ w_all,
                                              float* __restrict__ x,
                                              unsigned short* __restrict__ xb) {
    int bid = blockIdx.x;
    int tid = threadIdx.x;
    if (bid >= NB_WALL) {  // embed
        int idx = (bid - NB_WALL) * 256 + tid;
        int d = idx % DMODEL;
        int bt = idx / DMODEL;
        int t = bt % TLEN;
        float v = emb[(size_t)ids[bt] * DMODEL + d] + pos[t * DMODEL + d];
        x[idx] = v;
        xb[idx] = f2b(v);
        return;
    }
    int l = bid / NB_W;
    int i4 = ((bid % NB_W) * 256 + tid) * 4;
    unsigned short* wl = w_all + (size_t)l * WL;
    if (i4 < S_IP) {
        float4 v = *(const float4*)(ipw + (size_t)l * S_IP + i4);
        ushort4 o; o.x = f2b(v.x); o.y = f2b(v.y); o.z = f2b(v.z); o.w = f2b(v.w);
        *(ushort4*)(wl + i4) = o;
    } else if (i4 < S_IP + S_OP) {
        int i = i4 - S_IP;
        float4 v = *(const float4*)(opw + (size_t)l * S_OP + i);
        ushort4 o; o.x = f2b(v.x); o.y = f2b(v.y); o.z = f2b(v.z); o.w = f2b(v.w);
        *(ushort4*)(wl + S_IP + i) = o;
    } else if (i4 < S_IP + S_OP + S_XP2) {
        int i = i4 - S_IP - S_OP;
        int r = i / 1536, k = i % 1536;
        ushort4 o = {0, 0, 0, 0};
        if (r < 80) {
            float4 v = *(const float4*)(xpw + (size_t)l * (80 * 1536) + (size_t)r * 1536 + k);
            o.x = f2b(v.x); o.y = f2b(v.y); o.z = f2b(v.z); o.w = f2b(v.w);
        }
        *(ushort4*)(wl + S_IP + S_OP + i) = o;
    } else {
        int i = i4 - S_IP - S_OP - S_XP2;
        int r = i >> 6, k = i & 63;
        ushort4 o = {0, 0, 0, 0};
        if (k < DTRANK) {
            float4 v = *(const float4*)(dpw + (size_t)l * (DINNER * DTRANK) + (size_t)r * DTRANK + k);
            o.x = f2b(v.x); o.y = f2b(v.y); o.z = f2b(v.z); o.w = f2b(v.w);
        }
        *(ushort4*)(wl + S_IP + S_OP + S_XP2 + i) = o;
    }
}

// ---------------- bf16 MFMA GEMM, 2-phase LDS double-buffer, BM=64 ----------------
// D[row][col] = sum_k A[row,k]*B[col,k]; A,B bf16 row-major (k contiguous).
// MODE 0: o1 = xzT bf16 [3072][1024] (rows=e, cols=tok)                 (in_proj)
// MODE 3: o0 = x [1024][768] f32 accumulate, o1 = xb bf16 mirror        (out_proj)
template <int MODE>
__global__ __launch_bounds__(256) void mgemm_k(const unsigned short* __restrict__ A, int lda,
                                               const unsigned short* __restrict__ B, int ldb,
                                               int K,
                                               float* __restrict__ o0,
                                               unsigned short* __restrict__ o1) {
    __shared__ __align__(16) unsigned short Ab[2][64 * 64];
    __shared__ __align__(16) unsigned short Bb[2][64 * 64];

    int tid = threadIdx.x;
    int lane = tid & 63;
    int wave = tid >> 6;
    int wm = (wave >> 1) * 32;
    int wn = (wave & 1) * 32;
    int bm = blockIdx.x * 64;
    int bn = blockIdx.y * 64;
    int fr = lane & 15;
    int fq = lane >> 4;
    int fk = fq * 8;
    int srow = lane >> 3;
    int scol = (lane & 7) * 8;

    f32x4 acc[2][2] = {};

    auto stage = [&](int s, int k0) {
#pragma unroll
        for (int c = 0; c < 2; ++c) {
            int r = wave * 16 + c * 8;
            gload16(A + (size_t)(bm + r + srow) * lda + k0 + scol, &Ab[s][r * 64]);
            gload16(B + (size_t)(bn + r + srow) * ldb + k0 + scol, &Bb[s][r * 64]);
        }
    };

    int nk = K >> 6;
    stage(0, 0);
    asm volatile("s_waitcnt vmcnt(0)" ::: "memory");
    __builtin_amdgcn_s_barrier();

    for (int t = 0; t < nk; ++t) {
        int cur = t & 1;
        if (t + 1 < nk) stage(cur ^ 1, (t + 1) * 64);
#pragma unroll
        for (int ks = 0; ks < 2; ++ks) {
            int kk = ks * 32 + fk;
            bf16x8 af[2], bfr[2];
#pragma unroll
            for (int i = 0; i < 2; ++i)
                af[i] = *(const bf16x8*)&Ab[cur][(wm + i * 16 + fr) * 64 + kk];
#pragma unroll
            for (int j = 0; j < 2; ++j)
                bfr[j] = *(const bf16x8*)&Bb[cur][(wn + j * 16 + fr) * 64 + kk];
#pragma unroll
            for (int i = 0; i < 2; ++i)
#pragma unroll
                for (int j = 0; j < 2; ++j)
                    acc[i][j] = __builtin_amdgcn_mfma_f32_16x16x32_bf16(
                        af[i], bfr[j], acc[i][j], 0, 0, 0);
        }
        asm volatile("s_waitcnt vmcnt(0)" ::: "memory");
        __builtin_amdgcn_s_barrier();
    }

#pragma unroll
    for (int i = 0; i < 2; ++i) {
#pragma unroll
        for (int j = 0; j < 2; ++j) {
            int lc = wn + j * 16 + fr;
#pragma unroll
            for (int q = 0; q < 4; ++q) {
                int lr = wm + i * 16 + fq * 4 + q;
                float v = acc[i][j][q];
                if (MODE == 0) {
                    o1[(size_t)(bm + lr) * NTOK + bn + lc] = f2b(v);
                } else {  // MODE 3: residual accumulate + bf16 mirror
                    size_t idx = (size_t)(bm + lr) * DMODEL + bn + lc;
                    float nv = o0[idx] + v;
                    o0[idx] = nv;
                    o1[idx] = f2b(nv);
                }
            }
        }
    }
}

// ---------------- fused conv + x_proj + dt_proj ----------------
// grid (16) = token tiles of 64; 256 thr.  BM=128 feature rows.
// Phase 1: xdbl[128 feat][64 tok] = w_xp @ conv_silu(xz)^T (conv in B-staging)
//          -> Tt bf16 [tok][feat 0..63] (LDS), xdblT f32 rows 48..79 (global B,C)
// Phase 2: dtT[1536][tok-tile] = softplus(w_dt @ Tt + dpb), bf16
__global__ __launch_bounds__(256) void xproj_k(const unsigned short* __restrict__ xzT,
                                               const unsigned short* __restrict__ w_xp,
                                               const unsigned short* __restrict__ w_dt,
                                               const float* __restrict__ dpb,
                                               const float* __restrict__ cw,
                                               const float* __restrict__ cb,
                                               float* __restrict__ xdblT,
                                               unsigned short* __restrict__ dtT) {
    __shared__ __align__(16) unsigned short Ab[2][128 * 64];
    __shared__ __align__(16) unsigned short Bb[2][64 * 64];
    __shared__ __align__(16) unsigned short Tt[64 * 64];
    __shared__ float dpb_s[DINNER];

    int tid = threadIdx.x;
    int lane = tid & 63;
    int wave = tid >> 6;
    int bn = blockIdx.x;
    int tok0 = bn * 64;
    int wm = (wave >> 1) * 64;
    int wn = (wave & 1) * 32;
    int fr = lane & 15;
    int fq = lane >> 4;
    int fk = fq * 8;
    int srow = lane >> 3;
    int scol = (lane & 7) * 8;

    // conv-staging role: this thread owns d-offset cd_ within the k-slice,
    // token group cg (16 tokens)
    int cd_ = tid & 63;
    int cg = tid >> 6;
    bool atStart = ((bn & 3) == 0) && (cg == 0);  // batch-row boundary

    ushort4 bl[5];      // raw xz [t-4 .. t+15] for this (d, token-group)
    float4 cw4;
    float cbv;

    auto stageA = [&](int s, int k0) {
#pragma unroll
        for (int c = 0; c < 4; ++c) {
            int r = wave * 32 + c * 8;
            gload16(w_xp + (size_t)(r + srow) * DINNER + k0 + scol, &Ab[s][r * 64]);
        }
    };
    auto loadB = [&](int k0) {
        int d = k0 + cd_;
        const unsigned short* row = xzT + (size_t)d * NTOK + tok0 + cg * 16;
        ushort4 z4 = {0, 0, 0, 0};
        bl[0] = atStart ? z4 : *(const ushort4*)(row - 4);
#pragma unroll
        for (int c = 0; c < 4; ++c) bl[c + 1] = *(const ushort4*)(row + c * 4);
        cw4 = *(const float4*)(cw + d * 4);
        cbv = cb[d];
    };
    auto writeB = [&](int s) {
        float xw[20];
#pragma unroll
        for (int c = 0; c < 5; ++c) {
            xw[c * 4 + 0] = b2f(bl[c].x); xw[c * 4 + 1] = b2f(bl[c].y);
            xw[c * 4 + 2] = b2f(bl[c].z); xw[c * 4 + 3] = b2f(bl[c].w);
        }
#pragma unroll
        for (int u = 0; u < 16; ++u) {
            float sv = cbv + cw4.x * xw[u + 1] + cw4.y * xw[u + 2] +
                       cw4.z * xw[u + 3] + cw4.w * xw[u + 4];
            float v = sv / (1.f + __expf(-sv));
            Bb[s][(cg * 16 + u) * 64 + cd_] = f2b(v);  // contiguous 128B per row across wave
        }
    };

    f32x4 acc[4][2] = {};
    const int nk = DINNER / 64;  // 24

    loadB(0);
    stageA(0, 0);
    writeB(0);
    __syncthreads();

    for (int t = 0; t < nk; ++t) {
        int cur = t & 1;
        if (t + 1 < nk) {
            loadB((t + 1) * 64);       // issue global loads early
            stageA(cur ^ 1, (t + 1) * 64);
        }
#pragma unroll
        for (int ks = 0; ks < 2; ++ks) {
            int kk = ks * 32 + fk;
            bf16x8 af[4], bfr[2];
#pragma unroll
            for (int i = 0; i < 4; ++i)
                af[i] = *(const bf16x8*)&Ab[cur][(wm + i * 16 + fr) * 64 + kk];
#pragma unroll
            for (int j = 0; j < 2; ++j)
                bfr[j] = *(const bf16x8*)&Bb[cur][(wn + j * 16 + fr) * 64 + kk];
#pragma unroll
            for (int i = 0; i < 4; ++i)
#pragma unroll
                for (int j = 0; j < 2; ++j)
                    acc[i][j] = __builtin_amdgcn_mfma_f32_16x16x32_bf16(
                        af[i], bfr[j], acc[i][j], 0, 0, 0);
        }
        if (t + 1 < nk) writeB(cur ^ 1);  // conv VALU after MFMA issue
        __syncthreads();
    }

    // epilogue: Tt (feats 0..63, bf16, [tok][feat]) + global B,C rows 48..79 f32
#pragma unroll
    for (int i = 0; i < 4; ++i) {
#pragma unroll
        for (int j = 0; j < 2; ++j) {
            int lc = wn + j * 16 + fr;
#pragma unroll
            for (int q = 0; q < 4; ++q) {
                int lr = wm + i * 16 + fq * 4 + q;
                float v = acc[i][j][q];
                if (lr < 64) Tt[lc * 64 + lr] = f2b(v);
                if (lr >= 48 && lr < 80) xdblT[(size_t)lr * NTOK + tok0 + lc] = v;
            }
        }
    }
    for (int r = tid; r < DINNER; r += 256) dpb_s[r] = dpb[r];
    __syncthreads();

    // phase 2: dt GEMM over 24 tiles of [64 d][K=64], B = Tt
    int wm2 = (wave >> 1) * 32;
    int wn2 = (wave & 1) * 32;
    auto stageDt = [&](int s, int tile) {
#pragma unroll
        for (int c = 0; c < 2; ++c) {
            int r = wave * 16 + c * 8;
            gload16(w_dt + (size_t)(tile * 64 + r + srow) * 64 + scol, &Ab[s][r * 64]);
        }
    };
    stageDt(0, 0);
    __syncthreads();
    for (int tile = 0; tile < 24; ++tile) {
        int cur = tile & 1;
        if (tile + 1 < 24) stageDt(cur ^ 1, tile + 1);
        f32x4 a2[2][2] = {};
#pragma unroll
        for (int ks = 0; ks < 2; ++ks) {
            int kk = ks * 32 + fk;
            bf16x8 af[2], bfr[2];
#pragma unroll
            for (int i = 0; i < 2; ++i)
                af[i] = *(const bf16x8*)&Ab[cur][(wm2 + i * 16 + fr) * 64 + kk];
#pragma unroll
            for (int j = 0; j < 2; ++j)
                bfr[j] = *(const bf16x8*)&Tt[(wn2 + j * 16 + fr) * 64 + kk];
#pragma unroll
            for (int i = 0; i < 2; ++i)
#pragma unroll
                for (int j = 0; j < 2; ++j)
                    a2[i][j] = __builtin_amdgcn_mfma_f32_16x16x32_bf16(
                        af[i], bfr[j], a2[i][j], 0, 0, 0);
        }
#pragma unroll
        for (int i = 0; i < 2; ++i) {
#pragma unroll
            for (int j = 0; j < 2; ++j) {
                int tok = tok0 + wn2 + j * 16 + fr;
#pragma unroll
                for (int q = 0; q < 4; ++q) {
                    int d = tile * 64 + wm2 + i * 16 + fq * 4 + q;
                    float v = a2[i][j][q] + dpb_s[d];
                    v = (v > 0.f) ? v + log1pf(__expf(-v)) : log1pf(__expf(v));
                    dtT[(size_t)d * NTOK + tok] = f2b(v);
                }
            }
        }
        __syncthreads();
    }
}

// ---------------- selective scan, 8 waves x 32-step chunks, DPP reduce, inline conv ----
// grid (DINNER/4 = 384, BATCH), 512 threads; wave: 4 chains x 16 states.
__global__ __launch_bounds__(512) void scan_k(const unsigned short* __restrict__ dtT,
                                              const unsigned short* __restrict__ xzT,
                                              const float* __restrict__ xdblT,
                                              const float* __restrict__ cw,
                                              const float* __restrict__ cb,
                                              const float* __restrict__ Alog,
                                              const float* __restrict__ Dsk,
                                              unsigned short* __restrict__ ybb) {
    __shared__ float yl[4][260];
    __shared__ float cum[4][260];
    __shared__ float hL[8][4][16];
    __shared__ float Pb[8][4][16];
    __shared__ float Hin[8][4][16];

    int tid = threadIdx.x;
    int c = tid >> 6;
    int lane = tid & 63;
    int ch = lane >> 4;
    int n = lane & 15;
    int d = blockIdx.x * 4 + ch;
    int b = blockIdx.y;
    int tl0 = c * 32;

    float a = -__expf(Alog[(size_t)d * NSTATE + n]);
    float Dv = Dsk[d];
    float w0 = cw[d * 4 + 0], w1 = cw[d * 4 + 1], w2 = cw[d * 4 + 2], w3 = cw[d * 4 + 3];
    float cbv = cb[d];
    const unsigned short* dtp = dtT + (size_t)d * NTOK + b * TLEN + tl0;
    const unsigned short* xzp = xzT + (size_t)d * NTOK + b * TLEN + tl0;
    const float* Bp = xdblT + (size_t)(DTRANK + n) * NTOK + b * TLEN + tl0;
    const float* Cp = xdblT + (size_t)(DTRANK + NSTATE + n) * NTOK + b * TLEN + tl0;

    float hm3 = 0.f, hm2 = 0.f, hm1 = 0.f;
    if (tl0 > 0) {
        ushort4 pv = *(const ushort4*)(xzp - 4);
        hm3 = b2f(pv.y); hm2 = b2f(pv.z); hm1 = b2f(pv.w);
    }

    float h = 0.f, cd = 0.f;
    for (int t8 = 0; t8 < 32; t8 += 8) {
        ushort4 dv0 = *(const ushort4*)(dtp + t8), dv1 = *(const ushort4*)(dtp + t8 + 4);
        ushort4 xv0 = *(const ushort4*)(xzp + t8), xv1 = *(const ushort4*)(xzp + t8 + 4);
        float4 B0 = *(const float4*)(Bp + t8), B1 = *(const float4*)(Bp + t8 + 4);
        float4 C0 = *(const float4*)(Cp + t8), C1 = *(const float4*)(Cp + t8 + 4);
        float dts[8] = {b2f(dv0.x), b2f(dv0.y), b2f(dv0.z), b2f(dv0.w),
                        b2f(dv1.x), b2f(dv1.y), b2f(dv1.z), b2f(dv1.w)};
        float xw[11] = {hm3, hm2, hm1,
                        b2f(xv0.x), b2f(xv0.y), b2f(xv0.z), b2f(xv0.w),
                        b2f(xv1.x), b2f(xv1.y), b2f(xv1.z), b2f(xv1.w)};
        float Bs[8] = {B0.x, B0.y, B0.z, B0.w, B1.x, B1.y, B1.z, B1.w};
        float Cs[8] = {C0.x, C0.y, C0.z, C0.w, C1.x, C1.y, C1.z, C1.w};
#pragma unroll
        for (int u = 0; u < 8; ++u) {
            float sv = cbv + w0 * xw[u] + w1 * xw[u + 1] + w2 * xw[u + 2] + w3 * xw[u + 3];
            float xi = sv / (1.f + __expf(-sv));
            float dtv = dts[u];
            cd += dtv;
            float dA = __expf(dtv * a);
            h = dA * h + (dtv * xi) * Bs[u];
            float p = red16(h * Cs[u]);
            if (n == 0) {
                yl[ch][tl0 + t8 + u] = p + Dv * xi;
                cum[ch][tl0 + t8 + u] = cd;
            }
        }
        hm3 = xw[8]; hm2 = xw[9]; hm1 = xw[10];
    }
    hL[c][ch][n] = h;
    Pb[c][ch][n] = __expf(a * cd);
    __syncthreads();
    if (c == 0) {
        float H = 0.f;
        Hin[0][ch][n] = 0.f;
#pragma unroll
        for (int cc = 1; cc < 8; ++cc) {
            H = Pb[cc - 1][ch][n] * H + hL[cc - 1][ch][n];
            Hin[cc][ch][n] = H;
        }
    }
    __syncthreads();
    float Hv = Hin[c][ch][n];
    const unsigned short* zp = xzT + (size_t)(DINNER + d) * NTOK + b * TLEN + tl0;
    for (int t8 = 0; t8 < 32; t8 += 8) {
        float4 C0 = *(const float4*)(Cp + t8), C1 = *(const float4*)(Cp + t8 + 4);
        ushort4 zv0 = *(const ushort4*)(zp + t8), zv1 = *(const ushort4*)(zp + t8 + 4);
        float Cs[8] = {C0.x, C0.y, C0.z, C0.w, C1.x, C1.y, C1.z, C1.w};
        float zs[8] = {b2f(zv0.x), b2f(zv0.y), b2f(zv0.z), b2f(zv0.w),
                       b2f(zv1.x), b2f(zv1.y), b2f(zv1.z), b2f(zv1.w)};
#pragma unroll
        for (int u = 0; u < 8; ++u) {
            float cdt = cum[ch][tl0 + t8 + u];
            float corr = red16(Cs[u] * __expf(a * cdt) * Hv);
            if (n == 0) {
                float y = yl[ch][tl0 + t8 + u] + corr;
                float zz = zs[u];
                y *= zz / (1.f + __expf(-zz));
                yl[ch][tl0 + t8 + u] = y;
            }
        }
    }
    __syncthreads();
    if (tid < 256) {
        int t = tid;
        ushort4 o;
        o.x = f2b(yl[0][t]);
        o.y = f2b(yl[1][t]);
        o.z = f2b(yl[2][t]);
        o.w = f2b(yl[3][t]);
        *(ushort4*)(ybb + (size_t)(b * TLEN + t) * DINNER + blockIdx.x * 4) = o;
    }
}

// ---------------- RMSNorm ----------------
__global__ __launch_bounds__(256) void rmsnorm_k(const float* __restrict__ x,
                                                 const float* __restrict__ nw,
                                                 float* __restrict__ out) {
    int row = blockIdx.x;
    const float* xr = x + (size_t)row * DMODEL;
    int tid = threadIdx.x;
    float s = 0.f;
    for (int d = tid; d < DMODEL; d += 256) {
        float v = xr[d];
        s += v * v;
    }
#pragma unroll
    for (int off = 32; off >= 1; off >>= 1) s += __shfl_down(s, off);
    __shared__ float red[4];
    __shared__ float scale;
    int wid = tid >> 6, lane = tid & 63;
    if (lane == 0) red[wid] = s;
    __syncthreads();
    if (tid == 0) {
        float tot = red[0] + red[1] + red[2] + red[3];
        scale = rsqrtf(tot / (float)DMODEL + 1e-5f);
    }
    __syncthreads();
    float sc = scale;
    for (int d = tid; d < DMODEL; d += 256)
        out[(size_t)row * DMODEL + d] = xr[d] * sc * nw[d];
}

extern "C" void kernel_launch(void* const* d_in, const int* in_sizes, int n_in,
                              void* d_out, int out_size, void* d_ws, size_t ws_size,
                              hipStream_t stream) {
    const int* ids = (const int*)d_in[0];
    const float* emb = (const float*)d_in[1];
    const float* pos = (const float*)d_in[2];
    const float* ipw = (const float*)d_in[3];
    const float* cw = (const float*)d_in[4];
    const float* cb = (const float*)d_in[5];
    const float* xpw = (const float*)d_in[6];
    const float* dpw = (const float*)d_in[7];
    const float* dpb = (const float*)d_in[8];
    const float* Alog = (const float*)d_in[9];
    const float* Dsk = (const float*)d_in[10];
    const float* opw = (const float*)d_in[11];
    const float* nw = (const float*)d_in[12];

    float* x = (float*)d_ws;                             // 786432 f32
    float* xdblT = x + 786432;                           // 81920 f32
    unsigned short* xb = (unsigned short*)(xdblT + 81920);  // 786432
    unsigned short* xzT = xb + 786432;                   // 3145728
    unsigned short* dtT = xzT + 3145728;                 // 1572864
    unsigned short* ybb = dtT + 1572864;                 // 1572864
    unsigned short* w_all = ybb + 1572864;               // 4 * WL

    prep_k<<<NB_WALL + NB_E, 256, 0, stream>>>(ipw, opw, xpw, dpw, ids, emb, pos,
                                               w_all, x, xb);

    for (int l = 0; l < NLAYER; ++l) {
        const unsigned short* w_ip = w_all + (size_t)l * WL;
        const unsigned short* w_op = w_ip + S_IP;
        const unsigned short* w_xp = w_op + S_OP;
        const unsigned short* w_dt = w_xp + S_XP2;
        const float* cw_l = cw + (size_t)l * DINNER * 4;
        const float* cb_l = cb + (size_t)l * DINNER;
        const float* dpb_l = dpb + (size_t)l * DINNER;
        const float* Alog_l = Alog + (size_t)l * DINNER * NSTATE;
        const float* Dsk_l = Dsk + (size_t)l * DINNER;

        // in_proj: xzT bf16 [3072][1024]
        mgemm_k<0><<<dim3(3072 / 64, NTOK / 64), 256, 0, stream>>>(
            w_ip, DMODEL, xb, DMODEL, DMODEL, nullptr, xzT);
        // fused conv + x_proj + dt_proj
        xproj_k<<<16, 256, 0, stream>>>(xzT, w_xp, w_dt, dpb_l, cw_l, cb_l, xdblT, dtT);
        // scan (inline conv recompute + DPP reduce)
        scan_k<<<dim3(DINNER / 4, BATCH), 512, 0, stream>>>(
            dtT, xzT, xdblT, cw_l, cb_l, Alog_l, Dsk_l, ybb);
        // out_proj: x += y @ opw^T, xb = bf16(x)
        mgemm_k<3><<<dim3(NTOK / 64, DMODEL / 64), 256, 0, stream>>>(
            ybb, DINNER, w_op, DINNER, DINNER, x, xb);
    }

    rmsnorm_k<<<NTOK, 256, 0, stream>>>(x, nw, (float*)d_out);
}

// Round 9
// 514.792 us; speedup vs baseline: 2.0798x; 2.0798x over previous
//
#include <hip/hip_runtime.h>
#include <math.h>

#define TLEN 256
#define BATCH 4
#define DMODEL 768
#define DINNER 1536
#define NSTATE 16
#define DTRANK 48
#define NLAYER 4
#define NTOK 1024

#define S_IP 2359296
#define S_OP 1179648
#define S_XP2 196608            /* 128 x 1536 zero-padded */
#define S_DT 98304              /* 1536 x 64 zero-padded  */
#define WL (S_IP + S_OP + S_XP2 + S_DT)
#define NB_W (WL / 1024)
#define NB_WALL (NB_W * NLAYER)
#define NB_E (NTOK * DMODEL / 256)

typedef __bf16 bf16x8 __attribute__((ext_vector_type(8)));
typedef float f32x4 __attribute__((ext_vector_type(4)));

__device__ inline unsigned short f2b(float f) {
    union { float f; unsigned u; } v;
    v.f = f;
    unsigned r = (v.u + 0x7fffu + ((v.u >> 16) & 1u)) >> 16;  // RNE
    return (unsigned short)r;
}
__device__ inline float b2f(unsigned short u) {
    union { unsigned u; float f; } v;
    v.u = ((unsigned)u) << 16;
    return v.f;
}

__device__ inline void gload16(const void* g, void* l) {
    __builtin_amdgcn_global_load_lds(
        (const __attribute__((address_space(1))) void*)g,
        (__attribute__((address_space(3))) void*)l, 16, 0, 0);
}

// 16-lane sum via DPP (quad xor1, xor2, then row_ror 4, 8) — no DS ops.
__device__ inline float red16(float p) {
    p += __int_as_float(__builtin_amdgcn_update_dpp(0, __float_as_int(p), 0xB1, 0xf, 0xf, true));
    p += __int_as_float(__builtin_amdgcn_update_dpp(0, __float_as_int(p), 0x4E, 0xf, 0xf, true));
    p += __int_as_float(__builtin_amdgcn_update_dpp(0, __float_as_int(p), 0x124, 0xf, 0xf, true));
    p += __int_as_float(__builtin_amdgcn_update_dpp(0, __float_as_int(p), 0x128, 0xf, 0xf, true));
    return p;
}

// ---------------- prep: all-layer weight convert + embed, one dispatch ----------------
__global__ __launch_bounds__(256) void prep_k(const float* __restrict__ ipw,
                                              const float* __restrict__ opw,
                                              const float* __restrict__ xpw,
                                              const float* __restrict__ dpw,
                                              const int* __restrict__ ids,
                                              const float* __restrict__ emb,
                                              const float* __restrict__ pos,
                                              unsigned short* __restrict__ w_all,
                                              float* __restrict__ x,
                                              unsigned short* __restrict__ xb) {
    int bid = blockIdx.x;
    int tid = threadIdx.x;
    if (bid >= NB_WALL) {  // embed
        int idx = (bid - NB_WALL) * 256 + tid;
        int d = idx % DMODEL;
        int bt = idx / DMODEL;
        int t = bt % TLEN;
        float v = emb[(size_t)ids[bt] * DMODEL + d] + pos[t * DMODEL + d];
        x[idx] = v;
        xb[idx] = f2b(v);
        return;
    }
    int l = bid / NB_W;
    int i4 = ((bid % NB_W) * 256 + tid) * 4;
    unsigned short* wl = w_all + (size_t)l * WL;
    if (i4 < S_IP) {
        float4 v = *(const float4*)(ipw + (size_t)l * S_IP + i4);
        ushort4 o; o.x = f2b(v.x); o.y = f2b(v.y); o.z = f2b(v.z); o.w = f2b(v.w);
        *(ushort4*)(wl + i4) = o;
    } else if (i4 < S_IP + S_OP) {
        int i = i4 - S_IP;
        float4 v = *(const float4*)(opw + (size_t)l * S_OP + i);
        ushort4 o; o.x = f2b(v.x); o.y = f2b(v.y); o.z = f2b(v.z); o.w = f2b(v.w);
        *(ushort4*)(wl + S_IP + i) = o;
    } else if (i4 < S_IP + S_OP + S_XP2) {
        int i = i4 - S_IP - S_OP;
        int r = i / 1536, k = i % 1536;
        ushort4 o = {0, 0, 0, 0};
        if (r < 80) {
            float4 v = *(const float4*)(xpw + (size_t)l * (80 * 1536) + (size_t)r * 1536 + k);
            o.x = f2b(v.x); o.y = f2b(v.y); o.z = f2b(v.z); o.w = f2b(v.w);
        }
        *(ushort4*)(wl + S_IP + S_OP + i) = o;
    } else {
        int i = i4 - S_IP - S_OP - S_XP2;
        int r = i >> 6, k = i & 63;
        ushort4 o = {0, 0, 0, 0};
        if (k < DTRANK) {
            float4 v = *(const float4*)(dpw + (size_t)l * (DINNER * DTRANK) + (size_t)r * DTRANK + k);
            o.x = f2b(v.x); o.y = f2b(v.y); o.z = f2b(v.z); o.w = f2b(v.w);
        }
        *(ushort4*)(wl + S_IP + S_OP + S_XP2 + i) = o;
    }
}

// ---------------- bf16 MFMA GEMM, 2-phase LDS double-buffer, BM=64 ----------------
// D[row][col] = sum_k A[row,k]*B[col,k]; A,B bf16 row-major (k contiguous).
// MODE 0: o1 = xzT bf16 [3072][1024] (rows=e, cols=tok)                  (in_proj)
// MODE 1: o0 = xdblT f32 rows 48..79 only; o1 = xdblb bf16 [1024][64]
//         via LDS transpose, bm==0 blocks only                           (x_proj)
// MODE 2: o1 = dtT bf16 [1536][1024], softplus(v + bias[row])            (dt_proj)
// MODE 3: o0 = x [1024][768] f32 accumulate, o1 = xb bf16 mirror         (out_proj)
template <int MODE>
__global__ __launch_bounds__(256) void mgemm_k(const unsigned short* __restrict__ A, int lda,
                                               const unsigned short* __restrict__ B, int ldb,
                                               int K,
                                               const float* __restrict__ bias,
                                               float* __restrict__ o0,
                                               unsigned short* __restrict__ o1) {
    __shared__ __align__(16) unsigned short Ab[2][64 * 64];
    __shared__ __align__(16) unsigned short Bb[2][64 * 64];
    __shared__ float Tt[(MODE == 1) ? 64 * 64 : 1];

    int tid = threadIdx.x;
    int lane = tid & 63;
    int wave = tid >> 6;
    int wm = (wave >> 1) * 32;
    int wn = (wave & 1) * 32;
    int bm = blockIdx.x * 64;
    int bn = blockIdx.y * 64;
    int fr = lane & 15;
    int fq = lane >> 4;
    int fk = fq * 8;
    int srow = lane >> 3;
    int scol = (lane & 7) * 8;

    f32x4 acc[2][2] = {};

    auto stage = [&](int s, int k0) {
#pragma unroll
        for (int c = 0; c < 2; ++c) {
            int r = wave * 16 + c * 8;
            gload16(A + (size_t)(bm + r + srow) * lda + k0 + scol, &Ab[s][r * 64]);
            gload16(B + (size_t)(bn + r + srow) * ldb + k0 + scol, &Bb[s][r * 64]);
        }
    };

    int nk = K >> 6;
    stage(0, 0);
    asm volatile("s_waitcnt vmcnt(0)" ::: "memory");
    __builtin_amdgcn_s_barrier();

    for (int t = 0; t < nk; ++t) {
        int cur = t & 1;
        if (t + 1 < nk) stage(cur ^ 1, (t + 1) * 64);
#pragma unroll
        for (int ks = 0; ks < 2; ++ks) {
            int kk = ks * 32 + fk;
            bf16x8 af[2], bfr[2];
#pragma unroll
            for (int i = 0; i < 2; ++i)
                af[i] = *(const bf16x8*)&Ab[cur][(wm + i * 16 + fr) * 64 + kk];
#pragma unroll
            for (int j = 0; j < 2; ++j)
                bfr[j] = *(const bf16x8*)&Bb[cur][(wn + j * 16 + fr) * 64 + kk];
#pragma unroll
            for (int i = 0; i < 2; ++i)
#pragma unroll
                for (int j = 0; j < 2; ++j)
                    acc[i][j] = __builtin_amdgcn_mfma_f32_16x16x32_bf16(
                        af[i], bfr[j], acc[i][j], 0, 0, 0);
        }
        asm volatile("s_waitcnt vmcnt(0)" ::: "memory");
        __builtin_amdgcn_s_barrier();
    }

#pragma unroll
    for (int i = 0; i < 2; ++i) {
#pragma unroll
        for (int j = 0; j < 2; ++j) {
            int lc = wn + j * 16 + fr;
#pragma unroll
            for (int q = 0; q < 4; ++q) {
                int lr = wm + i * 16 + fq * 4 + q;
                float v = acc[i][j][q];
                if (MODE == 0) {
                    o1[(size_t)(bm + lr) * NTOK + bn + lc] = f2b(v);
                } else if (MODE == 1) {
                    int f = bm + lr;
                    if (f >= DTRANK && f < 80) o0[(size_t)f * NTOK + bn + lc] = v;
                    Tt[lc * 64 + lr] = v;
                } else if (MODE == 2) {
                    float s = v + bias[bm + lr];
                    s = (s > 0.f) ? s + log1pf(__expf(-s)) : log1pf(__expf(s));
                    o1[(size_t)(bm + lr) * NTOK + bn + lc] = f2b(s);
                } else {  // MODE 3: residual accumulate + bf16 mirror
                    size_t idx = (size_t)(bm + lr) * DMODEL + bn + lc;
                    float nv = o0[idx] + v;
                    o0[idx] = nv;
                    o1[idx] = f2b(nv);
                }
            }
        }
    }
    if (MODE == 1) {
        __syncthreads();
        if (bm == 0) {   // rows 0..63 = dt-feats (48) + B (zero-weighted in dt GEMM)
            int tok = tid >> 2;
            int fb = (tid & 3) * 16;
#pragma unroll
            for (int vv = 0; vv < 4; ++vv) {
                int f0 = fb + vv * 4;
                ushort4 o;
                o.x = f2b(Tt[tok * 64 + f0 + 0]);
                o.y = f2b(Tt[tok * 64 + f0 + 1]);
                o.z = f2b(Tt[tok * 64 + f0 + 2]);
                o.w = f2b(Tt[tok * 64 + f0 + 3]);
                *(ushort4*)(o1 + (size_t)(bn + tok) * 64 + f0) = o;
            }
        }
    }
}

// ---------------- causal dwconv(K=4) + bias + SiLU, bf16 in/out ----------------
__global__ __launch_bounds__(256) void conv_k(const unsigned short* __restrict__ xzT,
                                              const float* __restrict__ cw,
                                              const float* __restrict__ cb,
                                              unsigned short* __restrict__ xib) {
    __shared__ unsigned short tile[4][256];
    int tid = threadIdx.x;
    int ch = tid >> 6;
    int d = blockIdx.x * 4 + ch;
    int b = blockIdx.y;
    int t0 = (tid & 63) * 4;
    const unsigned short* src = xzT + (size_t)d * NTOK + b * TLEN + t0;
    ushort4 cur = *(const ushort4*)src;
    ushort4 prev = {0, 0, 0, 0};
    if (t0 > 0) prev = *(const ushort4*)(src - 4);
    float w0 = cw[d * 4 + 0], w1 = cw[d * 4 + 1], w2 = cw[d * 4 + 2], w3 = cw[d * 4 + 3];
    float bb = cb[d];
    float xw[8] = {b2f(prev.x), b2f(prev.y), b2f(prev.z), b2f(prev.w),
                   b2f(cur.x), b2f(cur.y), b2f(cur.z), b2f(cur.w)};
#pragma unroll
    for (int u = 0; u < 4; ++u) {
        float s = bb + w0 * xw[u + 1] + w1 * xw[u + 2] + w2 * xw[u + 3] + w3 * xw[u + 4];
        float v = s / (1.f + __expf(-s));
        tile[ch][t0 + u] = f2b(v);
    }
    __syncthreads();
    int t = tid;
    ushort4 o;
    o.x = tile[0][t]; o.y = tile[1][t]; o.z = tile[2][t]; o.w = tile[3][t];
    *(ushort4*)(xib + (size_t)(b * TLEN + t) * DINNER + blockIdx.x * 4) = o;
}

// ---------------- selective scan, 8 waves x 32-step chunks, DPP reduce, inline conv ----
__global__ __launch_bounds__(512) void scan_k(const unsigned short* __restrict__ dtT,
                                              const unsigned short* __restrict__ xzT,
                                              const float* __restrict__ xdblT,
                                              const float* __restrict__ cw,
                                              const float* __restrict__ cb,
                                              const float* __restrict__ Alog,
                                              const float* __restrict__ Dsk,
                                              unsigned short* __restrict__ ybb) {
    __shared__ float yl[4][260];
    __shared__ float cum[4][260];
    __shared__ float hL[8][4][16];
    __shared__ float Pb[8][4][16];
    __shared__ float Hin[8][4][16];

    int tid = threadIdx.x;
    int c = tid >> 6;
    int lane = tid & 63;
    int ch = lane >> 4;
    int n = lane & 15;
    int d = blockIdx.x * 4 + ch;
    int b = blockIdx.y;
    int tl0 = c * 32;

    float a = -__expf(Alog[(size_t)d * NSTATE + n]);
    float Dv = Dsk[d];
    float w0 = cw[d * 4 + 0], w1 = cw[d * 4 + 1], w2 = cw[d * 4 + 2], w3 = cw[d * 4 + 3];
    float cbv = cb[d];
    const unsigned short* dtp = dtT + (size_t)d * NTOK + b * TLEN + tl0;
    const unsigned short* xzp = xzT + (size_t)d * NTOK + b * TLEN + tl0;
    const float* Bp = xdblT + (size_t)(DTRANK + n) * NTOK + b * TLEN + tl0;
    const float* Cp = xdblT + (size_t)(DTRANK + NSTATE + n) * NTOK + b * TLEN + tl0;

    float hm3 = 0.f, hm2 = 0.f, hm1 = 0.f;
    if (tl0 > 0) {
        ushort4 pv = *(const ushort4*)(xzp - 4);
        hm3 = b2f(pv.y); hm2 = b2f(pv.z); hm1 = b2f(pv.w);
    }

    float h = 0.f, cd = 0.f;
    for (int t8 = 0; t8 < 32; t8 += 8) {
        ushort4 dv0 = *(const ushort4*)(dtp + t8), dv1 = *(const ushort4*)(dtp + t8 + 4);
        ushort4 xv0 = *(const ushort4*)(xzp + t8), xv1 = *(const ushort4*)(xzp + t8 + 4);
        float4 B0 = *(const float4*)(Bp + t8), B1 = *(const float4*)(Bp + t8 + 4);
        float4 C0 = *(const float4*)(Cp + t8), C1 = *(const float4*)(Cp + t8 + 4);
        float dts[8] = {b2f(dv0.x), b2f(dv0.y), b2f(dv0.z), b2f(dv0.w),
                        b2f(dv1.x), b2f(dv1.y), b2f(dv1.z), b2f(dv1.w)};
        float xw[11] = {hm3, hm2, hm1,
                        b2f(xv0.x), b2f(xv0.y), b2f(xv0.z), b2f(xv0.w),
                        b2f(xv1.x), b2f(xv1.y), b2f(xv1.z), b2f(xv1.w)};
        float Bs[8] = {B0.x, B0.y, B0.z, B0.w, B1.x, B1.y, B1.z, B1.w};
        float Cs[8] = {C0.x, C0.y, C0.z, C0.w, C1.x, C1.y, C1.z, C1.w};
#pragma unroll
        for (int u = 0; u < 8; ++u) {
            float sv = cbv + w0 * xw[u] + w1 * xw[u + 1] + w2 * xw[u + 2] + w3 * xw[u + 3];
            float xi = sv / (1.f + __expf(-sv));
            float dtv = dts[u];
            cd += dtv;
            float dA = __expf(dtv * a);
            h = dA * h + (dtv * xi) * Bs[u];
            float p = red16(h * Cs[u]);
            if (n == 0) {
                yl[ch][tl0 + t8 + u] = p + Dv * xi;
                cum[ch][tl0 + t8 + u] = cd;
            }
        }
        hm3 = xw[8]; hm2 = xw[9]; hm1 = xw[10];
    }
    hL[c][ch][n] = h;
    Pb[c][ch][n] = __expf(a * cd);
    __syncthreads();
    if (c == 0) {
        float H = 0.f;
        Hin[0][ch][n] = 0.f;
#pragma unroll
        for (int cc = 1; cc < 8; ++cc) {
            H = Pb[cc - 1][ch][n] * H + hL[cc - 1][ch][n];
            Hin[cc][ch][n] = H;
        }
    }
    __syncthreads();
    float Hv = Hin[c][ch][n];
    const unsigned short* zp = xzT + (size_t)(DINNER + d) * NTOK + b * TLEN + tl0;
    for (int t8 = 0; t8 < 32; t8 += 8) {
        float4 C0 = *(const float4*)(Cp + t8), C1 = *(const float4*)(Cp + t8 + 4);
        ushort4 zv0 = *(const ushort4*)(zp + t8), zv1 = *(const ushort4*)(zp + t8 + 4);
        float Cs[8] = {C0.x, C0.y, C0.z, C0.w, C1.x, C1.y, C1.z, C1.w};
        float zs[8] = {b2f(zv0.x), b2f(zv0.y), b2f(zv0.z), b2f(zv0.w),
                       b2f(zv1.x), b2f(zv1.y), b2f(zv1.z), b2f(zv1.w)};
#pragma unroll
        for (int u = 0; u < 8; ++u) {
            float cdt = cum[ch][tl0 + t8 + u];
            float corr = red16(Cs[u] * __expf(a * cdt) * Hv);
            if (n == 0) {
                float y = yl[ch][tl0 + t8 + u] + corr;
                float zz = zs[u];
                y *= zz / (1.f + __expf(-zz));
                yl[ch][tl0 + t8 + u] = y;
            }
        }
    }
    __syncthreads();
    if (tid < 256) {
        int t = tid;
        ushort4 o;
        o.x = f2b(yl[0][t]);
        o.y = f2b(yl[1][t]);
        o.z = f2b(yl[2][t]);
        o.w = f2b(yl[3][t]);
        *(ushort4*)(ybb + (size_t)(b * TLEN + t) * DINNER + blockIdx.x * 4) = o;
    }
}

// ---------------- RMSNorm ----------------
__global__ __launch_bounds__(256) void rmsnorm_k(const float* __restrict__ x,
                                                 const float* __restrict__ nw,
                                                 float* __restrict__ out) {
    int row = blockIdx.x;
    const float* xr = x + (size_t)row * DMODEL;
    int tid = threadIdx.x;
    float s = 0.f;
    for (int d = tid; d < DMODEL; d += 256) {
        float v = xr[d];
        s += v * v;
    }
#pragma unroll
    for (int off = 32; off >= 1; off >>= 1) s += __shfl_down(s, off);
    __shared__ float red[4];
    __shared__ float scale;
    int wid = tid >> 6, lane = tid & 63;
    if (lane == 0) red[wid] = s;
    __syncthreads();
    if (tid == 0) {
        float tot = red[0] + red[1] + red[2] + red[3];
        scale = rsqrtf(tot / (float)DMODEL + 1e-5f);
    }
    __syncthreads();
    float sc = scale;
    for (int d = tid; d < DMODEL; d += 256)
        out[(size_t)row * DMODEL + d] = xr[d] * sc * nw[d];
}

extern "C" void kernel_launch(void* const* d_in, const int* in_sizes, int n_in,
                              void* d_out, int out_size, void* d_ws, size_t ws_size,
                              hipStream_t stream) {
    const int* ids = (const int*)d_in[0];
    const float* emb = (const float*)d_in[1];
    const float* pos = (const float*)d_in[2];
    const float* ipw = (const float*)d_in[3];
    const float* cw = (const float*)d_in[4];
    const float* cb = (const float*)d_in[5];
    const float* xpw = (const float*)d_in[6];
    const float* dpw = (const float*)d_in[7];
    const float* dpb = (const float*)d_in[8];
    const float* Alog = (const float*)d_in[9];
    const float* Dsk = (const float*)d_in[10];
    const float* opw = (const float*)d_in[11];
    const float* nw = (const float*)d_in[12];

    float* x = (float*)d_ws;                             // 786432 f32
    float* xdblT = x + 786432;                           // 81920 f32
    unsigned short* xb = (unsigned short*)(xdblT + 81920);  // 786432
    unsigned short* xzT = xb + 786432;                   // 3145728
    unsigned short* xib = xzT + 3145728;                 // 1572864
    unsigned short* dtT = xib + 1572864;                 // 1572864
    unsigned short* ybb = dtT + 1572864;                 // 1572864
    unsigned short* xdblb = ybb + 1572864;               // 65536
    unsigned short* w_all = xdblb + 65536;               // 4 * WL

    prep_k<<<NB_WALL + NB_E, 256, 0, stream>>>(ipw, opw, xpw, dpw, ids, emb, pos,
                                               w_all, x, xb);

    for (int l = 0; l < NLAYER; ++l) {
        const unsigned short* w_ip = w_all + (size_t)l * WL;
        const unsigned short* w_op = w_ip + S_IP;
        const unsigned short* w_xp = w_op + S_OP;
        const unsigned short* w_dt = w_xp + S_XP2;
        const float* cw_l = cw + (size_t)l * DINNER * 4;
        const float* cb_l = cb + (size_t)l * DINNER;
        const float* dpb_l = dpb + (size_t)l * DINNER;
        const float* Alog_l = Alog + (size_t)l * DINNER * NSTATE;
        const float* Dsk_l = Dsk + (size_t)l * DINNER;

        // in_proj: xzT bf16 [3072][1024]
        mgemm_k<0><<<dim3(3072 / 64, NTOK / 64), 256, 0, stream>>>(
            w_ip, DMODEL, xb, DMODEL, DMODEL, nullptr, nullptr, xzT);
        // conv + silu -> xib bf16
        conv_k<<<dim3(DINNER / 4, BATCH), 256, 0, stream>>>(xzT, cw_l, cb_l, xib);
        // x_proj: xdblT f32 rows 48..79 + xdblb bf16 [1024][64]
        mgemm_k<1><<<dim3(2, NTOK / 64), 256, 0, stream>>>(
            w_xp, DINNER, xib, DINNER, DINNER, nullptr, xdblT, xdblb);
        // dt_proj: dtT bf16 = softplus(. + dpb), K=64
        mgemm_k<2><<<dim3(DINNER / 64, NTOK / 64), 256, 0, stream>>>(
            w_dt, 64, xdblb, 64, 64, dpb_l, nullptr, dtT);
        // scan
        scan_k<<<dim3(DINNER / 4, BATCH), 512, 0, stream>>>(
            dtT, xzT, xdblT, cw_l, cb_l, Alog_l, Dsk_l, ybb);
        // out_proj: x += y @ opw^T, xb = bf16(x)
        mgemm_k<3><<<dim3(NTOK / 64, DMODEL / 64), 256, 0, stream>>>(
            ybb, DINNER, w_op, DINNER, DINNER, nullptr, x, xb);
    }

    rmsnorm_k<<<NTOK, 256, 0, stream>>>(x, nw, (float*)d_out);
}